// Round 14
// baseline (245.793 us; speedup 1.0000x reference)
//
#include <hip/hip_runtime.h>
#include <hip/hip_bf16.h>
#include <cmath>

// Problem constants
#define BATCH   64
#define NPG     1024           // nodes per graph
#define NODES   65536          // BATCH*NPG
#define EDGES   524288
#define EPG     8192           // edges per graph (contiguous slice!)
#define FIN     14
#define NH      128
#define KP1     820
#define KP2     656
#define ASTR    15             // padded LDS stride for FIN tiles (2-way, free)
#define NG2BLK  16384          // gather2 blocks in merged dispatch

typedef __attribute__((ext_vector_type(8))) short bf16x8;
typedef __attribute__((ext_vector_type(4))) float f32x4;

static __device__ __forceinline__ unsigned short f2bf(float f) {
  __hip_bfloat16 h = __float2bfloat16(f);
  return *reinterpret_cast<unsigned short*>(&h);
}
static __device__ __forceinline__ float bf2f(unsigned int u16) {
  return __uint_as_float(u16 << 16);
}

// ---------------------------------------------------------------------------
// CSR build + Wfrag prep + ctr zeroing in ONE dispatch.
// Blocks 0..63: per-graph CSR (edges of graph g = slice [g*EPG,(g+1)*EPG)):
//   LDS histogram -> Hillis-Steele scan -> LDS-cursor fill.
// Blocks 64..67: bf16 W2 fragment table (4096 items); block 64 also zeroes
//   the per-graph completion counters used by k_readout2f.
// ---------------------------------------------------------------------------
__global__ __launch_bounds__(1024) void k_csr(
    const int* __restrict__ src, const int* __restrict__ dst,
    int* __restrict__ rowptr, int* __restrict__ col,
    const float* __restrict__ W2rel, const float* __restrict__ W2rt,
    unsigned short* __restrict__ Wfrag, int* __restrict__ ctr) {
  int g = blockIdx.x, t = threadIdx.x;
  if (g >= BATCH) {                           // Wfrag builder blocks
    if (g == BATCH && t < BATCH) ctr[t] = 0;  // zero per-graph counters
    int id = (g - BATCH) * 1024 + t;          // 0..4095
    int lane = id & 63, sg = (id >> 6) & 7, c = id >> 9;
    const float* SW = (sg < 4) ? W2rel : W2rt;
    int o = c * 16 + (lane & 15);
    int k = (sg & 3) * 32 + (lane >> 4) * 8;
    float4 f0 = *(const float4*)(SW + (size_t)o * NH + k);
    float4 f1 = *(const float4*)(SW + (size_t)o * NH + k + 4);
    union { unsigned short us[8]; uint4 v; } p;
    p.us[0] = f2bf(f0.x); p.us[1] = f2bf(f0.y);
    p.us[2] = f2bf(f0.z); p.us[3] = f2bf(f0.w);
    p.us[4] = f2bf(f1.x); p.us[5] = f2bf(f1.y);
    p.us[6] = f2bf(f1.z); p.us[7] = f2bf(f1.w);
    *(uint4*)(Wfrag + (size_t)id * 8) = p.v;
    return;
  }
  __shared__ int cnt[NPG];
  int ebase = g * EPG;
  cnt[t] = 0;
  __syncthreads();
  int dl[8], sl[8];
#pragma unroll
  for (int i = 0; i < 8; ++i) {
    int e = ebase + t + i * 1024;
    dl[i] = dst[e] - g * NPG;
    sl[i] = src[e];
    atomicAdd(&cnt[dl[i]], 1);
  }
  __syncthreads();
  int v = cnt[t];
  for (int d = 1; d < NPG; d <<= 1) {       // inclusive scan, in place
    int add = (t >= d) ? cnt[t - d] : 0;
    __syncthreads();
    cnt[t] += add;
    __syncthreads();
  }
  int excl = cnt[t] - v;
  rowptr[g * NPG + t] = ebase + excl;
  if (g == 0 && t == 0) rowptr[NODES] = EDGES;
  __syncthreads();
  cnt[t] = excl;                            // becomes local cursor
  __syncthreads();
#pragma unroll
  for (int i = 0; i < 8; ++i) {
    int pos = atomicAdd(&cnt[dl[i]], 1);
    col[ebase + pos] = sl[i];
  }
}

// ---------------------------------------------------------------------------
// conv1 aggregation via CSR gather (XCD-swizzled; high occupancy, unfused —
// r9/r10: fusing gathers into GEMMs kills the TLP they depend on)
// ---------------------------------------------------------------------------
__global__ __launch_bounds__(256) void k_gather1(
    const float* __restrict__ x, const int* __restrict__ rowptr,
    const int* __restrict__ col, float* __restrict__ agg1) {
  int bid = blockIdx.x;                       // 4096 blocks, 512 per XCD chunk
  int swz = (bid & 7) * 512 + (bid >> 3);
  int t = threadIdx.x;
  int gi = t >> 4, l = t & 15;
  int n = swz * 16 + gi;
  int rs = rowptr[n], re = rowptr[n + 1];
  if (l < FIN) {
    float acc = 0.f;
    for (int j = rs; j < re; ++j) {
      int v = col[j];
      acc += x[(size_t)v * FIN + l];
    }
    agg1[(size_t)n * FIN + l] = acc;
  }
}

// ---------------------------------------------------------------------------
// conv1 GEMM + relu + fused pool1 score; OUTPUT IS BF16. LDS stride ASTR=15.
// ---------------------------------------------------------------------------
__global__ __launch_bounds__(256) void k_gemm1(
    const float* __restrict__ x, const float* __restrict__ agg1,
    const float* __restrict__ Wrel, const float* __restrict__ brel,
    const float* __restrict__ Wroot, const float* __restrict__ p1w,
    unsigned short* __restrict__ hbf1, float* __restrict__ s1) {
  __shared__ float As[64 * ASTR];
  __shared__ float Xs[64 * ASTR];
  __shared__ float Wl[2 * FIN][NH];
  int t = threadIdx.x;
  int nb = blockIdx.x * 64;
  for (int i = t; i < 64 * FIN; i += 256) {
    int n = i / FIN, k = i - n * FIN;
    As[n * ASTR + k] = agg1[(size_t)nb * FIN + i];
    Xs[n * ASTR + k] = x[(size_t)nb * FIN + i];
  }
  for (int i = t; i < NH * FIN; i += 256) {
    int o = i / FIN, k = i - o * FIN;
    Wl[k][o]       = Wrel[i];
    Wl[k + FIN][o] = Wroot[i];
  }
  __syncthreads();
  int og = t & 15, ng = t >> 4, ra = ng * 4;
  float bb[8], pw[8];
#pragma unroll
  for (int j = 0; j < 4; ++j) {
    int c0 = og * 4 + j, c1 = 64 + og * 4 + j;
    bb[j] = brel[c0]; bb[j + 4] = brel[c1];
    pw[j] = p1w[c0];  pw[j + 4] = p1w[c1];
  }
  float q = 0.f;
#pragma unroll
  for (int j = 0; j < 8; ++j) q += pw[j] * pw[j];
  q += __shfl_xor(q, 1); q += __shfl_xor(q, 2);
  q += __shfl_xor(q, 4); q += __shfl_xor(q, 8);
  float rnorm = rsqrtf(q);

  float acc[4][8];
#pragma unroll
  for (int i = 0; i < 4; ++i)
#pragma unroll
    for (int j = 0; j < 8; ++j) acc[i][j] = bb[j];
#pragma unroll
  for (int k = 0; k < FIN; ++k) {
    float4 w0 = *(const float4*)&Wl[k][og * 4];
    float4 w1 = *(const float4*)&Wl[k][64 + og * 4];
#pragma unroll
    for (int i = 0; i < 4; ++i) {
      float a = As[(ra + i) * ASTR + k];
      acc[i][0] += a * w0.x; acc[i][1] += a * w0.y;
      acc[i][2] += a * w0.z; acc[i][3] += a * w0.w;
      acc[i][4] += a * w1.x; acc[i][5] += a * w1.y;
      acc[i][6] += a * w1.z; acc[i][7] += a * w1.w;
    }
  }
#pragma unroll
  for (int k = 0; k < FIN; ++k) {
    float4 w0 = *(const float4*)&Wl[FIN + k][og * 4];
    float4 w1 = *(const float4*)&Wl[FIN + k][64 + og * 4];
#pragma unroll
    for (int i = 0; i < 4; ++i) {
      float a = Xs[(ra + i) * ASTR + k];
      acc[i][0] += a * w0.x; acc[i][1] += a * w0.y;
      acc[i][2] += a * w0.z; acc[i][3] += a * w0.w;
      acc[i][4] += a * w1.x; acc[i][5] += a * w1.y;
      acc[i][6] += a * w1.z; acc[i][7] += a * w1.w;
    }
  }
#pragma unroll
  for (int i = 0; i < 4; ++i) {
    int n = nb + ra + i;
    float pv = 0.f;
    union { unsigned short us[4]; uint2 v; } o0, o1;
#pragma unroll
    for (int j = 0; j < 4; ++j) {
      float v0 = fmaxf(acc[i][j], 0.f);
      float v1 = fmaxf(acc[i][4 + j], 0.f);
      pv += v0 * pw[j] + v1 * pw[4 + j];
      o0.us[j] = f2bf(v0);
      o1.us[j] = f2bf(v1);
    }
    *(uint2*)(hbf1 + (size_t)n * NH + og * 4) = o0.v;
    *(uint2*)(hbf1 + (size_t)n * NH + 64 + og * 4) = o1.v;
    pv += __shfl_xor(pv, 1);
    pv += __shfl_xor(pv, 2);
    pv += __shfl_xor(pv, 4);
    pv += __shfl_xor(pv, 8);
    if (og == 0) s1[n] = tanhf(pv * rnorm);
  }
}

// ---------------------------------------------------------------------------
// exact per-graph top-K: 512 threads, bitonic over 1024 keys; j<=64 stages
// are wave-local. Writes kept[], and (if sm_out) sm_out[n]=kept?score:0.
// ---------------------------------------------------------------------------
__global__ __launch_bounds__(512) void k_topk(
    const float* __restrict__ score, const int* __restrict__ mask_in,
    int* __restrict__ kept, float* __restrict__ sm_out, int K) {
  __shared__ unsigned long long keys[1024];
  int t = threadIdx.x, g = blockIdx.x;
  for (int i = t; i < 1024; i += 512) {
    int n = g * NPG + i;
    unsigned int inv;
    if (mask_in && !mask_in[n]) {
      inv = 0xFFFFFFFFu;
    } else {
      unsigned int u   = __float_as_uint(score[n]);
      unsigned int ord = (u & 0x80000000u) ? ~u : (u | 0x80000000u);
      inv = ~ord;
    }
    keys[i] = ((unsigned long long)inv << 32) | (unsigned int)i;
  }
  __syncthreads();
  for (int k = 2; k <= 1024; k <<= 1) {
    int j = k >> 1;
    for (; j >= 128; j >>= 1) {            // cross-wave stages
      int i = ((t & ~(j - 1)) << 1) | (t & (j - 1));
      int p = i | j;
      unsigned long long a = keys[i], b = keys[p];
      bool up = ((i & k) == 0);
      if ((a > b) == up) { keys[i] = b; keys[p] = a; }
      __syncthreads();
    }
    for (; j > 0; j >>= 1) {               // wave-local stages
      int i = ((t & ~(j - 1)) << 1) | (t & (j - 1));
      int p = i | j;
      unsigned long long a = keys[i], b = keys[p];
      bool up = ((i & k) == 0);
      if ((a > b) == up) { keys[i] = b; keys[p] = a; }
      asm volatile("" ::: "memory");
    }
    __syncthreads();
  }
  for (int i = t; i < 1024; i += 512) {
    int idx = (int)(keys[i] & 0xFFFFFFFFu);
    int n = g * NPG + idx;
    int kp = (i < K) ? 1 : 0;
    kept[n] = kp;
    if (sm_out) sm_out[n] = kp ? score[n] : 0.f;
  }
}

// ---------------------------------------------------------------------------
// MERGED dispatch: gather2 (blocks 0..16383) + readout1 (blocks 16384..17407).
// Both depend only on topk1's outputs (kept1, s1m) — independent of each
// other; merging saves a dispatch and overlaps BW-bound readout with the
// latency-bound gather.
// gather2: one wave per kept dst row, coalesced 256B bf16 row loads from
//   hbf1, per-edge scale s1m (shfl-broadcast). Output bf16. XCD-swizzled.
// readout1: psum/pmax partials over kept rows (r12 form, 2 rows in flight).
// ---------------------------------------------------------------------------
__global__ __launch_bounds__(256) void k_gather2ro(
    const unsigned short* __restrict__ hbf1, const float* __restrict__ s1,
    const float* __restrict__ s1m, const int* __restrict__ rowptr,
    const int* __restrict__ col, const int* __restrict__ kept1,
    unsigned short* __restrict__ agg2bf, float* __restrict__ psum,
    float* __restrict__ pmax) {
  int bid = blockIdx.x;
  if (bid >= NG2BLK) {                        // ---- readout1 path ----
    int rb = bid - NG2BLK;                    // 0..1023
    int g = rb >> 4, c = rb & 15;
    int f = threadIdx.x & 127, half = threadIdx.x >> 7;
    int nbase = g * NPG + c * 64 + half;
    float sum = 0.f, mx = -1e30f;
    for (int i = 0; i < 64; i += 2) {
      int n = nbase + i;
      if (kept1[n]) {
        float v = bf2f(hbf1[(size_t)n * NH + f]) * s1[n];
        sum += v;
        mx = fmaxf(mx, v);
      }
    }
    int slot = rb * 2 + half;
    psum[(size_t)slot * NH + f] = sum;
    pmax[(size_t)slot * NH + f] = mx;
    return;
  }
  // ---- gather2 path ----
  int swz = (bid & 7) * 2048 + (bid >> 3);
  int wave = threadIdx.x >> 6, lane = threadIdx.x & 63;
  int d = swz * 4 + wave;
  if (!kept1[d]) return;                      // row never consumed downstream
  int rs = rowptr[d], re = rowptr[d + 1];
  int deg = re - rs;
  int colv = 0; float sv = 0.f;
  if (lane < deg) {
    colv = col[rs + lane];
    sv = s1m[colv];
  }
  int m = deg < 64 ? deg : 64;
  float ax = 0.f, ay = 0.f;
  int nfull = m & ~3;
  int j = 0;
  for (; j < nfull; j += 4) {
    int v0 = __shfl(colv, j);
    int v1 = __shfl(colv, j + 1);
    int v2 = __shfl(colv, j + 2);
    int v3 = __shfl(colv, j + 3);
    float f0 = __shfl(sv, j);
    float f1 = __shfl(sv, j + 1);
    float f2 = __shfl(sv, j + 2);
    float f3 = __shfl(sv, j + 3);
    unsigned int p0 = *(const unsigned int*)(hbf1 + (size_t)v0 * NH + lane * 2);
    unsigned int p1 = *(const unsigned int*)(hbf1 + (size_t)v1 * NH + lane * 2);
    unsigned int p2 = *(const unsigned int*)(hbf1 + (size_t)v2 * NH + lane * 2);
    unsigned int p3 = *(const unsigned int*)(hbf1 + (size_t)v3 * NH + lane * 2);
    ax += bf2f(p0 & 0xffff) * f0 + bf2f(p1 & 0xffff) * f1 +
          bf2f(p2 & 0xffff) * f2 + bf2f(p3 & 0xffff) * f3;
    ay += bf2f(p0 >> 16) * f0 + bf2f(p1 >> 16) * f1 +
          bf2f(p2 >> 16) * f2 + bf2f(p3 >> 16) * f3;
  }
  for (; j < m; ++j) {
    int v = __shfl(colv, j);
    float f = __shfl(sv, j);
    unsigned int p = *(const unsigned int*)(hbf1 + (size_t)v * NH + lane * 2);
    ax += bf2f(p & 0xffff) * f;
    ay += bf2f(p >> 16) * f;
  }
  for (int jj = rs + 64; jj < re; ++jj) {      // deg>64 fallback (≈never)
    int v = col[jj];
    float f = s1m[v];
    unsigned int p = *(const unsigned int*)(hbf1 + (size_t)v * NH + lane * 2);
    ax += bf2f(p & 0xffff) * f;
    ay += bf2f(p >> 16) * f;
  }
  unsigned int packed = ((unsigned int)f2bf(ay) << 16) | (unsigned int)f2bf(ax);
  *(unsigned int*)(agg2bf + (size_t)d * NH + lane * 2) = packed;
}

// ---------------------------------------------------------------------------
// conv2 GEMM via bf16 MFMA — barrier-free, LDS-free. 2 row-groups/wave
// (W fragment reuse x2). A: agg2bf direct; root = hbf1*s1m (in-register).
// Output h2 is bf16, gated. Dropped rows: finite poison in, masked out.
// D layout: col=lane&15, row=(lane>>4)*4+reg (m89). XCD-swizzled.
// ---------------------------------------------------------------------------
__global__ __launch_bounds__(256) void k_gemm2(
    const unsigned short* __restrict__ agg2bf,
    const unsigned short* __restrict__ hbf1, const float* __restrict__ s1m,
    const int* __restrict__ kept1, const unsigned short* __restrict__ Wfrag,
    const float* __restrict__ b2, const float* __restrict__ p2w,
    unsigned short* __restrict__ h2bf, float* __restrict__ s2) {
  int t = threadIdx.x;
  int bid = blockIdx.x;                 // 512 blocks, 64 per XCD chunk
  int swz = (bid & 7) * 64 + (bid >> 3);
  int nb = swz * 128;
  int lane = t & 63, w = t >> 6;
  int row16 = lane & 15, kgrp = lane >> 4;
  int base = nb + 32 * w;               // wave owns rows base..base+31
  int r0 = base + row16, r1 = base + 16 + row16;

  // ---- A fragments ----
  bf16x8 a0[8], a1[8];
#pragma unroll
  for (int s = 0; s < 4; ++s) {
    int k = s * 32 + kgrp * 8;
    a0[s] = *(const bf16x8*)(agg2bf + (size_t)r0 * NH + k);
    a1[s] = *(const bf16x8*)(agg2bf + (size_t)r1 * NH + k);
  }
  {
    float sc0 = s1m[r0], sc1 = s1m[r1];
    const unsigned short* S0 = hbf1 + (size_t)r0 * NH;
    const unsigned short* S1 = hbf1 + (size_t)r1 * NH;
#pragma unroll
    for (int s = 0; s < 4; ++s) {
      int k = s * 32 + kgrp * 8;
      union { unsigned short us[8]; uint4 v; } i0, i1;
      i0.v = *(const uint4*)(S0 + k);
      i1.v = *(const uint4*)(S1 + k);
      union { unsigned short us[8]; bf16x8 v; } p, q;
#pragma unroll
      for (int u = 0; u < 8; ++u) {
        p.us[u] = f2bf(bf2f(i0.us[u]) * sc0);
        q.us[u] = f2bf(bf2f(i1.us[u]) * sc1);
      }
      a0[4 + s] = p.v;
      a1[4 + s] = q.v;
    }
  }

  // ---- MFMA: stream W fragments from L2, reuse x2 ----
  f32x4 acc0[8], acc1[8];
#pragma unroll
  for (int c = 0; c < 8; ++c) {
    acc0[c] = (f32x4){0.f, 0.f, 0.f, 0.f};
    acc1[c] = (f32x4){0.f, 0.f, 0.f, 0.f};
  }
  const bf16x8* WF = (const bf16x8*)Wfrag;
#pragma unroll
  for (int c = 0; c < 8; ++c) {
#pragma unroll
    for (int s = 0; s < 8; ++s) {
      bf16x8 wv = WF[(c * 8 + s) * 64 + lane];
      acc0[c] = __builtin_amdgcn_mfma_f32_16x16x32_bf16(a0[s], wv, acc0[c], 0, 0, 0);
      acc1[c] = __builtin_amdgcn_mfma_f32_16x16x32_bf16(a1[s], wv, acc1[c], 0, 0, 0);
    }
  }

  // ---- epilogue ----
  float bb[8], pw[8];
#pragma unroll
  for (int c = 0; c < 8; ++c) {
    bb[c] = b2[c * 16 + row16];
    pw[c] = p2w[c * 16 + row16];
  }
  float q2 = 0.f;
#pragma unroll
  for (int c = 0; c < 8; ++c) q2 += pw[c] * pw[c];
  q2 += __shfl_xor(q2, 1); q2 += __shfl_xor(q2, 2);
  q2 += __shfl_xor(q2, 4); q2 += __shfl_xor(q2, 8);
  float rnorm = rsqrtf(q2);

#pragma unroll
  for (int g2 = 0; g2 < 2; ++g2) {
    f32x4* acc = g2 ? acc1 : acc0;
    int rbase = base + g2 * 16;
    int msr[4];
#pragma unroll
    for (int r = 0; r < 4; ++r) msr[r] = kept1[rbase + kgrp * 4 + r];
    float pvp[4] = {0.f, 0.f, 0.f, 0.f};
#pragma unroll
    for (int c = 0; c < 8; ++c) {
#pragma unroll
      for (int r = 0; r < 4; ++r) {
        float u = fmaxf(acc[c][r] + bb[c], 0.f);
        pvp[r] += u * pw[c];
        if (msr[r]) {                    // kept2 subset of kept1 -> safe skip
          int n = rbase + kgrp * 4 + r;
          h2bf[(size_t)n * NH + c * 16 + row16] = f2bf(u);
        }
      }
    }
#pragma unroll
    for (int r = 0; r < 4; ++r) {
      float pv = pvp[r];
      pv += __shfl_xor(pv, 1);
      pv += __shfl_xor(pv, 2);
      pv += __shfl_xor(pv, 4);
      pv += __shfl_xor(pv, 8);
      if (row16 == 0) {
        int n = rbase + kgrp * 4 + r;
        s2[n] = tanhf(pv * rnorm);
      }
    }
  }
}

// ---------------------------------------------------------------------------
// readout2 + fused final combine. 1024 blocks; each graph has 16 blocks.
// After writing its 2 slots, a block bumps the graph's counter; the LAST
// block of each graph (release/acquire via __threadfence + device atomic)
// reduces all 32 psum/pmax slots of both layers and writes out[g].
// Deterministic: fixed slots, fixed reduce order, single combiner.
// ---------------------------------------------------------------------------
__global__ __launch_bounds__(256) void k_readout2f(
    const unsigned short* __restrict__ h, const float* __restrict__ s,
    const int* __restrict__ kept, float* __restrict__ psum2,
    float* __restrict__ pmax2, const float* __restrict__ psum1,
    const float* __restrict__ pmax1, float* __restrict__ out,
    int* __restrict__ ctr) {
  int g = blockIdx.x >> 4, c = blockIdx.x & 15;
  int f = threadIdx.x & 127, half = threadIdx.x >> 7;
  int nbase = g * NPG + c * 64 + half;
  float sum = 0.f, mx = -1e30f;
  for (int i = 0; i < 64; i += 2) {
    int n = nbase + i;
    if (kept[n]) {
      float v = bf2f(h[(size_t)n * NH + f]) * s[n];
      sum += v;
      mx = fmaxf(mx, v);
    }
  }
  int slot = blockIdx.x * 2 + half;
  psum2[(size_t)slot * NH + f] = sum;
  pmax2[(size_t)slot * NH + f] = mx;

  __threadfence();
  __syncthreads();
  __shared__ int amLast;
  if (threadIdx.x == 0) amLast = (atomicAdd(&ctr[g], 1) == 15);
  __syncthreads();
  if (!amLast) return;
  __threadfence();
  int t = threadIdx.x;
  if (t < 128) {
    float a = 0.f, b = 0.f;
#pragma unroll 4
    for (int cc = 0; cc < 32; ++cc) {
      a += psum1[(size_t)(g * 32 + cc) * NH + t];
      b += psum2[(size_t)(g * 32 + cc) * NH + t];
    }
    out[(size_t)g * 256 + t] = a / (float)KP1 + b / (float)KP2;
  } else {
    int ff = t - 128;
    float a = -1e30f, b = -1e30f;
#pragma unroll 4
    for (int cc = 0; cc < 32; ++cc) {
      a = fmaxf(a, pmax1[(size_t)(g * 32 + cc) * NH + ff]);
      b = fmaxf(b, pmax2[(size_t)(g * 32 + cc) * NH + ff]);
    }
    out[(size_t)g * 256 + t] = a + b;
  }
}

// ---------------------------------------------------------------------------
extern "C" void kernel_launch(void* const* d_in, const int* in_sizes, int n_in,
                              void* d_out, int out_size, void* d_ws, size_t ws_size,
                              hipStream_t stream) {
  const float* x     = (const float*)d_in[0];
  const int*   eidx  = (const int*)d_in[1];
  const int*   src   = eidx;
  const int*   dst   = eidx + EDGES;
  const float* W1rel = (const float*)d_in[3];
  const float* b1    = (const float*)d_in[4];
  const float* W1rt  = (const float*)d_in[5];
  const float* p1w   = (const float*)d_in[6];
  const float* W2rel = (const float*)d_in[7];
  const float* b2    = (const float*)d_in[8];
  const float* W2rt  = (const float*)d_in[9];
  const float* p2w   = (const float*)d_in[10];
  float* out = (float*)d_out;

  // workspace layout (floats)
  float* ws = (float*)d_ws;
  size_t off = 0;
  unsigned short* hbf1   = (unsigned short*)(ws + off); off += (size_t)NODES * NH / 2;
  unsigned short* h2bf   = (unsigned short*)(ws + off); off += (size_t)NODES * NH / 2;
  unsigned short* agg2bf = (unsigned short*)(ws + off); off += (size_t)NODES * NH / 2;
  float* agg1  = ws + off; off += (size_t)NODES * FIN;
  float* s1    = ws + off; off += NODES;
  float* s2    = ws + off; off += NODES;
  float* s1m   = ws + off; off += NODES;
  int*   kept1 = (int*)(ws + off); off += NODES;
  int*   kept2 = (int*)(ws + off); off += NODES;
  float* psum1 = ws + off; off += 2048 * NH;
  float* pmax1 = ws + off; off += 2048 * NH;
  float* psum2 = ws + off; off += 2048 * NH;
  float* pmax2 = ws + off; off += 2048 * NH;
  unsigned short* Wfrag = (unsigned short*)(ws + off); off += 16384; // 64 KB
  int*   ctr     = (int*)(ws + off); off += BATCH;
  int*   rowptr  = (int*)(ws + off); off += NODES + 1;
  int*   col     = (int*)(ws + off); off += EDGES;

  // ---- CSR build + W fragment prep + ctr zero (one dispatch) ----
  k_csr<<<BATCH + 4, 1024, 0, stream>>>(src, dst, rowptr, col, W2rel, W2rt,
                                        Wfrag, ctr);

  // ---- layer 1 ----
  k_gather1<<<NODES / 16, 256, 0, stream>>>(x, rowptr, col, agg1);
  k_gemm1<<<NODES / 64, 256, 0, stream>>>(x, agg1, W1rel, b1, W1rt, p1w,
                                          hbf1, s1);
  k_topk<<<BATCH, 512, 0, stream>>>(s1, nullptr, kept1, s1m, KP1);

  // ---- merged: conv2 gather + layer-1 readout ----
  k_gather2ro<<<NG2BLK + 1024, 256, 0, stream>>>(hbf1, s1, s1m, rowptr, col,
                                                 kept1, agg2bf, psum1, pmax1);

  // ---- layer 2 ----
  k_gemm2<<<NODES / 128, 256, 0, stream>>>(agg2bf, hbf1, s1m, kept1, Wfrag,
                                           b2, p2w, h2bf, s2);
  k_topk<<<BATCH, 512, 0, stream>>>(s2, kept1, kept2, nullptr, KP2);
  k_readout2f<<<1024, 256, 0, stream>>>(h2bf, s2, kept2, psum2, pmax2,
                                        psum1, pmax1, out, ctr);
}

// Round 15
// 162.198 us; speedup vs baseline: 1.5154x; 1.5154x over previous
//
#include <hip/hip_runtime.h>
#include <hip/hip_bf16.h>
#include <cmath>

// Problem constants
#define BATCH   64
#define NPG     1024           // nodes per graph
#define NODES   65536          // BATCH*NPG
#define EDGES   524288
#define EPG     8192           // edges per graph (contiguous slice!)
#define FIN     14
#define NH      128
#define KP1     820
#define KP2     656
#define ASTR    15             // padded LDS stride for FIN tiles (2-way, free)
#define NG2BLK  16384          // gather2 blocks in merged dispatch

typedef __attribute__((ext_vector_type(8))) short bf16x8;
typedef __attribute__((ext_vector_type(4))) float f32x4;

static __device__ __forceinline__ unsigned short f2bf(float f) {
  __hip_bfloat16 h = __float2bfloat16(f);
  return *reinterpret_cast<unsigned short*>(&h);
}
static __device__ __forceinline__ float bf2f(unsigned int u16) {
  return __uint_as_float(u16 << 16);
}

// ---------------------------------------------------------------------------
// CSR build + Wfrag prep in ONE dispatch.
// Blocks 0..63: per-graph CSR (edges of graph g = slice [g*EPG,(g+1)*EPG)):
//   LDS histogram -> Hillis-Steele scan -> LDS-cursor fill.
// Blocks 64..67: bf16 W2 fragment table (4096 items).
// ---------------------------------------------------------------------------
__global__ __launch_bounds__(1024) void k_csr(
    const int* __restrict__ src, const int* __restrict__ dst,
    int* __restrict__ rowptr, int* __restrict__ col,
    const float* __restrict__ W2rel, const float* __restrict__ W2rt,
    unsigned short* __restrict__ Wfrag) {
  int g = blockIdx.x, t = threadIdx.x;
  if (g >= BATCH) {                           // Wfrag builder blocks
    int id = (g - BATCH) * 1024 + t;          // 0..4095
    int lane = id & 63, sg = (id >> 6) & 7, c = id >> 9;
    const float* SW = (sg < 4) ? W2rel : W2rt;
    int o = c * 16 + (lane & 15);
    int k = (sg & 3) * 32 + (lane >> 4) * 8;
    float4 f0 = *(const float4*)(SW + (size_t)o * NH + k);
    float4 f1 = *(const float4*)(SW + (size_t)o * NH + k + 4);
    union { unsigned short us[8]; uint4 v; } p;
    p.us[0] = f2bf(f0.x); p.us[1] = f2bf(f0.y);
    p.us[2] = f2bf(f0.z); p.us[3] = f2bf(f0.w);
    p.us[4] = f2bf(f1.x); p.us[5] = f2bf(f1.y);
    p.us[6] = f2bf(f1.z); p.us[7] = f2bf(f1.w);
    *(uint4*)(Wfrag + (size_t)id * 8) = p.v;
    return;
  }
  __shared__ int cnt[NPG];
  int ebase = g * EPG;
  cnt[t] = 0;
  __syncthreads();
  int dl[8], sl[8];
#pragma unroll
  for (int i = 0; i < 8; ++i) {
    int e = ebase + t + i * 1024;
    dl[i] = dst[e] - g * NPG;
    sl[i] = src[e];
    atomicAdd(&cnt[dl[i]], 1);
  }
  __syncthreads();
  int v = cnt[t];
  for (int d = 1; d < NPG; d <<= 1) {       // inclusive scan, in place
    int add = (t >= d) ? cnt[t - d] : 0;
    __syncthreads();
    cnt[t] += add;
    __syncthreads();
  }
  int excl = cnt[t] - v;
  rowptr[g * NPG + t] = ebase + excl;
  if (g == 0 && t == 0) rowptr[NODES] = EDGES;
  __syncthreads();
  cnt[t] = excl;                            // becomes local cursor
  __syncthreads();
#pragma unroll
  for (int i = 0; i < 8; ++i) {
    int pos = atomicAdd(&cnt[dl[i]], 1);
    col[ebase + pos] = sl[i];
  }
}

// ---------------------------------------------------------------------------
// conv1 aggregation via CSR gather (XCD-swizzled; high occupancy, unfused —
// r9/r10: fusing gathers into GEMMs kills the TLP they depend on)
// ---------------------------------------------------------------------------
__global__ __launch_bounds__(256) void k_gather1(
    const float* __restrict__ x, const int* __restrict__ rowptr,
    const int* __restrict__ col, float* __restrict__ agg1) {
  int bid = blockIdx.x;                       // 4096 blocks, 512 per XCD chunk
  int swz = (bid & 7) * 512 + (bid >> 3);
  int t = threadIdx.x;
  int gi = t >> 4, l = t & 15;
  int n = swz * 16 + gi;
  int rs = rowptr[n], re = rowptr[n + 1];
  if (l < FIN) {
    float acc = 0.f;
    for (int j = rs; j < re; ++j) {
      int v = col[j];
      acc += x[(size_t)v * FIN + l];
    }
    agg1[(size_t)n * FIN + l] = acc;
  }
}

// ---------------------------------------------------------------------------
// conv1 GEMM + relu + fused pool1 score; OUTPUT IS BF16. LDS stride ASTR=15.
// ---------------------------------------------------------------------------
__global__ __launch_bounds__(256) void k_gemm1(
    const float* __restrict__ x, const float* __restrict__ agg1,
    const float* __restrict__ Wrel, const float* __restrict__ brel,
    const float* __restrict__ Wroot, const float* __restrict__ p1w,
    unsigned short* __restrict__ hbf1, float* __restrict__ s1) {
  __shared__ float As[64 * ASTR];
  __shared__ float Xs[64 * ASTR];
  __shared__ float Wl[2 * FIN][NH];
  int t = threadIdx.x;
  int nb = blockIdx.x * 64;
  for (int i = t; i < 64 * FIN; i += 256) {
    int n = i / FIN, k = i - n * FIN;
    As[n * ASTR + k] = agg1[(size_t)nb * FIN + i];
    Xs[n * ASTR + k] = x[(size_t)nb * FIN + i];
  }
  for (int i = t; i < NH * FIN; i += 256) {
    int o = i / FIN, k = i - o * FIN;
    Wl[k][o]       = Wrel[i];
    Wl[k + FIN][o] = Wroot[i];
  }
  __syncthreads();
  int og = t & 15, ng = t >> 4, ra = ng * 4;
  float bb[8], pw[8];
#pragma unroll
  for (int j = 0; j < 4; ++j) {
    int c0 = og * 4 + j, c1 = 64 + og * 4 + j;
    bb[j] = brel[c0]; bb[j + 4] = brel[c1];
    pw[j] = p1w[c0];  pw[j + 4] = p1w[c1];
  }
  float q = 0.f;
#pragma unroll
  for (int j = 0; j < 8; ++j) q += pw[j] * pw[j];
  q += __shfl_xor(q, 1); q += __shfl_xor(q, 2);
  q += __shfl_xor(q, 4); q += __shfl_xor(q, 8);
  float rnorm = rsqrtf(q);

  float acc[4][8];
#pragma unroll
  for (int i = 0; i < 4; ++i)
#pragma unroll
    for (int j = 0; j < 8; ++j) acc[i][j] = bb[j];
#pragma unroll
  for (int k = 0; k < FIN; ++k) {
    float4 w0 = *(const float4*)&Wl[k][og * 4];
    float4 w1 = *(const float4*)&Wl[k][64 + og * 4];
#pragma unroll
    for (int i = 0; i < 4; ++i) {
      float a = As[(ra + i) * ASTR + k];
      acc[i][0] += a * w0.x; acc[i][1] += a * w0.y;
      acc[i][2] += a * w0.z; acc[i][3] += a * w0.w;
      acc[i][4] += a * w1.x; acc[i][5] += a * w1.y;
      acc[i][6] += a * w1.z; acc[i][7] += a * w1.w;
    }
  }
#pragma unroll
  for (int k = 0; k < FIN; ++k) {
    float4 w0 = *(const float4*)&Wl[FIN + k][og * 4];
    float4 w1 = *(const float4*)&Wl[FIN + k][64 + og * 4];
#pragma unroll
    for (int i = 0; i < 4; ++i) {
      float a = Xs[(ra + i) * ASTR + k];
      acc[i][0] += a * w0.x; acc[i][1] += a * w0.y;
      acc[i][2] += a * w0.z; acc[i][3] += a * w0.w;
      acc[i][4] += a * w1.x; acc[i][5] += a * w1.y;
      acc[i][6] += a * w1.z; acc[i][7] += a * w1.w;
    }
  }
#pragma unroll
  for (int i = 0; i < 4; ++i) {
    int n = nb + ra + i;
    float pv = 0.f;
    union { unsigned short us[4]; uint2 v; } o0, o1;
#pragma unroll
    for (int j = 0; j < 4; ++j) {
      float v0 = fmaxf(acc[i][j], 0.f);
      float v1 = fmaxf(acc[i][4 + j], 0.f);
      pv += v0 * pw[j] + v1 * pw[4 + j];
      o0.us[j] = f2bf(v0);
      o1.us[j] = f2bf(v1);
    }
    *(uint2*)(hbf1 + (size_t)n * NH + og * 4) = o0.v;
    *(uint2*)(hbf1 + (size_t)n * NH + 64 + og * 4) = o1.v;
    pv += __shfl_xor(pv, 1);
    pv += __shfl_xor(pv, 2);
    pv += __shfl_xor(pv, 4);
    pv += __shfl_xor(pv, 8);
    if (og == 0) s1[n] = tanhf(pv * rnorm);
  }
}

// ---------------------------------------------------------------------------
// exact per-graph top-K: 512 threads, bitonic over 1024 keys; j<=64 stages
// are wave-local. Writes kept[], and (if sm_out) sm_out[n]=kept?score:0.
// ---------------------------------------------------------------------------
__global__ __launch_bounds__(512) void k_topk(
    const float* __restrict__ score, const int* __restrict__ mask_in,
    int* __restrict__ kept, float* __restrict__ sm_out, int K) {
  __shared__ unsigned long long keys[1024];
  int t = threadIdx.x, g = blockIdx.x;
  for (int i = t; i < 1024; i += 512) {
    int n = g * NPG + i;
    unsigned int inv;
    if (mask_in && !mask_in[n]) {
      inv = 0xFFFFFFFFu;
    } else {
      unsigned int u   = __float_as_uint(score[n]);
      unsigned int ord = (u & 0x80000000u) ? ~u : (u | 0x80000000u);
      inv = ~ord;
    }
    keys[i] = ((unsigned long long)inv << 32) | (unsigned int)i;
  }
  __syncthreads();
  for (int k = 2; k <= 1024; k <<= 1) {
    int j = k >> 1;
    for (; j >= 128; j >>= 1) {            // cross-wave stages
      int i = ((t & ~(j - 1)) << 1) | (t & (j - 1));
      int p = i | j;
      unsigned long long a = keys[i], b = keys[p];
      bool up = ((i & k) == 0);
      if ((a > b) == up) { keys[i] = b; keys[p] = a; }
      __syncthreads();
    }
    for (; j > 0; j >>= 1) {               // wave-local stages
      int i = ((t & ~(j - 1)) << 1) | (t & (j - 1));
      int p = i | j;
      unsigned long long a = keys[i], b = keys[p];
      bool up = ((i & k) == 0);
      if ((a > b) == up) { keys[i] = b; keys[p] = a; }
      asm volatile("" ::: "memory");
    }
    __syncthreads();
  }
  for (int i = t; i < 1024; i += 512) {
    int idx = (int)(keys[i] & 0xFFFFFFFFu);
    int n = g * NPG + idx;
    int kp = (i < K) ? 1 : 0;
    kept[n] = kp;
    if (sm_out) sm_out[n] = kp ? score[n] : 0.f;
  }
}

// ---------------------------------------------------------------------------
// MERGED dispatch: gather2 (blocks 0..16383) + readout1 (blocks 16384..17407).
// Both depend only on topk1's outputs (kept1, s1m) — independent of each
// other; merging saves a dispatch and overlaps BW-bound readout with the
// latency-bound gather. NO device-scope fences (r14 lesson: __threadfence
// in a BW-bound kernel = L2 writeback storm, 10x slowdown).
// ---------------------------------------------------------------------------
__global__ __launch_bounds__(256) void k_gather2ro(
    const unsigned short* __restrict__ hbf1, const float* __restrict__ s1,
    const float* __restrict__ s1m, const int* __restrict__ rowptr,
    const int* __restrict__ col, const int* __restrict__ kept1,
    unsigned short* __restrict__ agg2bf, float* __restrict__ psum,
    float* __restrict__ pmax) {
  int bid = blockIdx.x;
  if (bid >= NG2BLK) {                        // ---- readout1 path ----
    int rb = bid - NG2BLK;                    // 0..1023
    int g = rb >> 4, c = rb & 15;
    int f = threadIdx.x & 127, half = threadIdx.x >> 7;
    int nbase = g * NPG + c * 64 + half;
    float sum = 0.f, mx = -1e30f;
    for (int i = 0; i < 64; i += 2) {
      int n = nbase + i;
      if (kept1[n]) {
        float v = bf2f(hbf1[(size_t)n * NH + f]) * s1[n];
        sum += v;
        mx = fmaxf(mx, v);
      }
    }
    int slot = rb * 2 + half;
    psum[(size_t)slot * NH + f] = sum;
    pmax[(size_t)slot * NH + f] = mx;
    return;
  }
  // ---- gather2 path ----
  int swz = (bid & 7) * 2048 + (bid >> 3);
  int wave = threadIdx.x >> 6, lane = threadIdx.x & 63;
  int d = swz * 4 + wave;
  if (!kept1[d]) return;                      // row never consumed downstream
  int rs = rowptr[d], re = rowptr[d + 1];
  int deg = re - rs;
  int colv = 0; float sv = 0.f;
  if (lane < deg) {
    colv = col[rs + lane];
    sv = s1m[colv];
  }
  int m = deg < 64 ? deg : 64;
  float ax = 0.f, ay = 0.f;
  int nfull = m & ~3;
  int j = 0;
  for (; j < nfull; j += 4) {
    int v0 = __shfl(colv, j);
    int v1 = __shfl(colv, j + 1);
    int v2 = __shfl(colv, j + 2);
    int v3 = __shfl(colv, j + 3);
    float f0 = __shfl(sv, j);
    float f1 = __shfl(sv, j + 1);
    float f2 = __shfl(sv, j + 2);
    float f3 = __shfl(sv, j + 3);
    unsigned int p0 = *(const unsigned int*)(hbf1 + (size_t)v0 * NH + lane * 2);
    unsigned int p1 = *(const unsigned int*)(hbf1 + (size_t)v1 * NH + lane * 2);
    unsigned int p2 = *(const unsigned int*)(hbf1 + (size_t)v2 * NH + lane * 2);
    unsigned int p3 = *(const unsigned int*)(hbf1 + (size_t)v3 * NH + lane * 2);
    ax += bf2f(p0 & 0xffff) * f0 + bf2f(p1 & 0xffff) * f1 +
          bf2f(p2 & 0xffff) * f2 + bf2f(p3 & 0xffff) * f3;
    ay += bf2f(p0 >> 16) * f0 + bf2f(p1 >> 16) * f1 +
          bf2f(p2 >> 16) * f2 + bf2f(p3 >> 16) * f3;
  }
  for (; j < m; ++j) {
    int v = __shfl(colv, j);
    float f = __shfl(sv, j);
    unsigned int p = *(const unsigned int*)(hbf1 + (size_t)v * NH + lane * 2);
    ax += bf2f(p & 0xffff) * f;
    ay += bf2f(p >> 16) * f;
  }
  for (int jj = rs + 64; jj < re; ++jj) {      // deg>64 fallback (≈never)
    int v = col[jj];
    float f = s1m[v];
    unsigned int p = *(const unsigned int*)(hbf1 + (size_t)v * NH + lane * 2);
    ax += bf2f(p & 0xffff) * f;
    ay += bf2f(p >> 16) * f;
  }
  unsigned int packed = ((unsigned int)f2bf(ay) << 16) | (unsigned int)f2bf(ax);
  *(unsigned int*)(agg2bf + (size_t)d * NH + lane * 2) = packed;
}

// ---------------------------------------------------------------------------
// conv2 GEMM via bf16 MFMA — barrier-free, LDS-free. 2 row-groups/wave
// (W fragment reuse x2). A: agg2bf direct; root = hbf1*s1m (in-register).
// Output h2 is bf16, gated. Dropped rows: finite poison in, masked out.
// D layout: col=lane&15, row=(lane>>4)*4+reg (m89). XCD-swizzled.
// ---------------------------------------------------------------------------
__global__ __launch_bounds__(256) void k_gemm2(
    const unsigned short* __restrict__ agg2bf,
    const unsigned short* __restrict__ hbf1, const float* __restrict__ s1m,
    const int* __restrict__ kept1, const unsigned short* __restrict__ Wfrag,
    const float* __restrict__ b2, const float* __restrict__ p2w,
    unsigned short* __restrict__ h2bf, float* __restrict__ s2) {
  int t = threadIdx.x;
  int bid = blockIdx.x;                 // 512 blocks, 64 per XCD chunk
  int swz = (bid & 7) * 64 + (bid >> 3);
  int nb = swz * 128;
  int lane = t & 63, w = t >> 6;
  int row16 = lane & 15, kgrp = lane >> 4;
  int base = nb + 32 * w;               // wave owns rows base..base+31
  int r0 = base + row16, r1 = base + 16 + row16;

  // ---- A fragments ----
  bf16x8 a0[8], a1[8];
#pragma unroll
  for (int s = 0; s < 4; ++s) {
    int k = s * 32 + kgrp * 8;
    a0[s] = *(const bf16x8*)(agg2bf + (size_t)r0 * NH + k);
    a1[s] = *(const bf16x8*)(agg2bf + (size_t)r1 * NH + k);
  }
  {
    float sc0 = s1m[r0], sc1 = s1m[r1];
    const unsigned short* S0 = hbf1 + (size_t)r0 * NH;
    const unsigned short* S1 = hbf1 + (size_t)r1 * NH;
#pragma unroll
    for (int s = 0; s < 4; ++s) {
      int k = s * 32 + kgrp * 8;
      union { unsigned short us[8]; uint4 v; } i0, i1;
      i0.v = *(const uint4*)(S0 + k);
      i1.v = *(const uint4*)(S1 + k);
      union { unsigned short us[8]; bf16x8 v; } p, q;
#pragma unroll
      for (int u = 0; u < 8; ++u) {
        p.us[u] = f2bf(bf2f(i0.us[u]) * sc0);
        q.us[u] = f2bf(bf2f(i1.us[u]) * sc1);
      }
      a0[4 + s] = p.v;
      a1[4 + s] = q.v;
    }
  }

  // ---- MFMA: stream W fragments from L2, reuse x2 ----
  f32x4 acc0[8], acc1[8];
#pragma unroll
  for (int c = 0; c < 8; ++c) {
    acc0[c] = (f32x4){0.f, 0.f, 0.f, 0.f};
    acc1[c] = (f32x4){0.f, 0.f, 0.f, 0.f};
  }
  const bf16x8* WF = (const bf16x8*)Wfrag;
#pragma unroll
  for (int c = 0; c < 8; ++c) {
#pragma unroll
    for (int s = 0; s < 8; ++s) {
      bf16x8 wv = WF[(c * 8 + s) * 64 + lane];
      acc0[c] = __builtin_amdgcn_mfma_f32_16x16x32_bf16(a0[s], wv, acc0[c], 0, 0, 0);
      acc1[c] = __builtin_amdgcn_mfma_f32_16x16x32_bf16(a1[s], wv, acc1[c], 0, 0, 0);
    }
  }

  // ---- epilogue ----
  float bb[8], pw[8];
#pragma unroll
  for (int c = 0; c < 8; ++c) {
    bb[c] = b2[c * 16 + row16];
    pw[c] = p2w[c * 16 + row16];
  }
  float q2 = 0.f;
#pragma unroll
  for (int c = 0; c < 8; ++c) q2 += pw[c] * pw[c];
  q2 += __shfl_xor(q2, 1); q2 += __shfl_xor(q2, 2);
  q2 += __shfl_xor(q2, 4); q2 += __shfl_xor(q2, 8);
  float rnorm = rsqrtf(q2);

#pragma unroll
  for (int g2 = 0; g2 < 2; ++g2) {
    f32x4* acc = g2 ? acc1 : acc0;
    int rbase = base + g2 * 16;
    int msr[4];
#pragma unroll
    for (int r = 0; r < 4; ++r) msr[r] = kept1[rbase + kgrp * 4 + r];
    float pvp[4] = {0.f, 0.f, 0.f, 0.f};
#pragma unroll
    for (int c = 0; c < 8; ++c) {
#pragma unroll
      for (int r = 0; r < 4; ++r) {
        float u = fmaxf(acc[c][r] + bb[c], 0.f);
        pvp[r] += u * pw[c];
        if (msr[r]) {                    // kept2 subset of kept1 -> safe skip
          int n = rbase + kgrp * 4 + r;
          h2bf[(size_t)n * NH + c * 16 + row16] = f2bf(u);
        }
      }
    }
#pragma unroll
    for (int r = 0; r < 4; ++r) {
      float pv = pvp[r];
      pv += __shfl_xor(pv, 1);
      pv += __shfl_xor(pv, 2);
      pv += __shfl_xor(pv, 4);
      pv += __shfl_xor(pv, 8);
      if (row16 == 0) {
        int n = rbase + kgrp * 4 + r;
        s2[n] = tanhf(pv * rnorm);
      }
    }
  }
}

// ---------------------------------------------------------------------------
// readout2 partials (plain r12 form — no fences, no atomics)
// ---------------------------------------------------------------------------
__global__ __launch_bounds__(256) void k_readout2(
    const unsigned short* __restrict__ h, const float* __restrict__ s,
    const int* __restrict__ kept, float* __restrict__ psum,
    float* __restrict__ pmax) {
  int g = blockIdx.x >> 4, c = blockIdx.x & 15;
  int f = threadIdx.x & 127, half = threadIdx.x >> 7;
  int nbase = g * NPG + c * 64 + half;
  float sum = 0.f, mx = -1e30f;
  for (int i = 0; i < 64; i += 2) {
    int n = nbase + i;
    if (kept[n]) {
      float v = bf2f(h[(size_t)n * NH + f]) * s[n];
      sum += v;
      mx = fmaxf(mx, v);
    }
  }
  int slot = blockIdx.x * 2 + half;
  psum[(size_t)slot * NH + f] = sum;
  pmax[(size_t)slot * NH + f] = mx;
}

// ---------------------------------------------------------------------------
// final combine (32 partial slots per graph per layer)
// ---------------------------------------------------------------------------
__global__ __launch_bounds__(256) void k_final(
    const float* __restrict__ psum1, const float* __restrict__ pmax1,
    const float* __restrict__ psum2, const float* __restrict__ pmax2,
    float* __restrict__ out) {
  int g = blockIdx.x, t = threadIdx.x;
  if (t < 128) {
    float a = 0.f, b = 0.f;
#pragma unroll
    for (int c = 0; c < 32; ++c) {
      a += psum1[(size_t)(g * 32 + c) * NH + t];
      b += psum2[(size_t)(g * 32 + c) * NH + t];
    }
    out[(size_t)g * 256 + t] = a / (float)KP1 + b / (float)KP2;
  } else {
    int f = t - 128;
    float a = -1e30f, b = -1e30f;
#pragma unroll
    for (int c = 0; c < 32; ++c) {
      a = fmaxf(a, pmax1[(size_t)(g * 32 + c) * NH + f]);
      b = fmaxf(b, pmax2[(size_t)(g * 32 + c) * NH + f]);
    }
    out[(size_t)g * 256 + t] = a + b;
  }
}

// ---------------------------------------------------------------------------
extern "C" void kernel_launch(void* const* d_in, const int* in_sizes, int n_in,
                              void* d_out, int out_size, void* d_ws, size_t ws_size,
                              hipStream_t stream) {
  const float* x     = (const float*)d_in[0];
  const int*   eidx  = (const int*)d_in[1];
  const int*   src   = eidx;
  const int*   dst   = eidx + EDGES;
  const float* W1rel = (const float*)d_in[3];
  const float* b1    = (const float*)d_in[4];
  const float* W1rt  = (const float*)d_in[5];
  const float* p1w   = (const float*)d_in[6];
  const float* W2rel = (const float*)d_in[7];
  const float* b2    = (const float*)d_in[8];
  const float* W2rt  = (const float*)d_in[9];
  const float* p2w   = (const float*)d_in[10];
  float* out = (float*)d_out;

  // workspace layout (floats)
  float* ws = (float*)d_ws;
  size_t off = 0;
  unsigned short* hbf1   = (unsigned short*)(ws + off); off += (size_t)NODES * NH / 2;
  unsigned short* h2bf   = (unsigned short*)(ws + off); off += (size_t)NODES * NH / 2;
  unsigned short* agg2bf = (unsigned short*)(ws + off); off += (size_t)NODES * NH / 2;
  float* agg1  = ws + off; off += (size_t)NODES * FIN;
  float* s1    = ws + off; off += NODES;
  float* s2    = ws + off; off += NODES;
  float* s1m   = ws + off; off += NODES;
  int*   kept1 = (int*)(ws + off); off += NODES;
  int*   kept2 = (int*)(ws + off); off += NODES;
  float* psum1 = ws + off; off += 2048 * NH;
  float* pmax1 = ws + off; off += 2048 * NH;
  float* psum2 = ws + off; off += 2048 * NH;
  float* pmax2 = ws + off; off += 2048 * NH;
  unsigned short* Wfrag = (unsigned short*)(ws + off); off += 16384; // 64 KB
  int*   rowptr  = (int*)(ws + off); off += NODES + 1;
  int*   col     = (int*)(ws + off); off += EDGES;

  // ---- CSR build + W fragment prep (one dispatch) ----
  k_csr<<<BATCH + 4, 1024, 0, stream>>>(src, dst, rowptr, col, W2rel, W2rt,
                                        Wfrag);

  // ---- layer 1 ----
  k_gather1<<<NODES / 16, 256, 0, stream>>>(x, rowptr, col, agg1);
  k_gemm1<<<NODES / 64, 256, 0, stream>>>(x, agg1, W1rel, b1, W1rt, p1w,
                                          hbf1, s1);
  k_topk<<<BATCH, 512, 0, stream>>>(s1, nullptr, kept1, s1m, KP1);

  // ---- merged: conv2 gather + layer-1 readout ----
  k_gather2ro<<<NG2BLK + 1024, 256, 0, stream>>>(hbf1, s1, s1m, rowptr, col,
                                                 kept1, agg2bf, psum1, pmax1);

  // ---- layer 2 ----
  k_gemm2<<<NODES / 128, 256, 0, stream>>>(agg2bf, hbf1, s1m, kept1, Wfrag,
                                           b2, p2w, h2bf, s2);
  k_topk<<<BATCH, 512, 0, stream>>>(s2, kept1, kept2, nullptr, KP2);
  k_readout2<<<1024, 256, 0, stream>>>(h2bf, s2, kept2, psum2, pmax2);
  k_final<<<BATCH, 256, 0, stream>>>(psum1, pmax1, psum2, pmax2, out);
}

// Round 17
// 161.047 us; speedup vs baseline: 1.5262x; 1.0071x over previous
//
#include <hip/hip_runtime.h>
#include <hip/hip_bf16.h>
#include <cmath>

// Problem constants
#define BATCH   64
#define NPG     1024           // nodes per graph
#define NODES   65536          // BATCH*NPG
#define EDGES   524288
#define EPG     8192           // edges per graph (contiguous slice!)
#define FIN     14
#define NH      128
#define KP1     820
#define KP2     656
#define ASTR    15             // padded LDS stride for FIN tiles (2-way, free)
#define NG2BLK  16384          // gather2 blocks in merged dispatch

typedef __attribute__((ext_vector_type(8))) short bf16x8;
typedef __attribute__((ext_vector_type(4))) float f32x4;

static __device__ __forceinline__ unsigned short f2bf(float f) {
  __hip_bfloat16 h = __float2bfloat16(f);
  return *reinterpret_cast<unsigned short*>(&h);
}
static __device__ __forceinline__ float bf2f(unsigned int u16) {
  return __uint_as_float(u16 << 16);
}

// ---------------------------------------------------------------------------
// CSR build + Wfrag prep in ONE dispatch.
// Blocks 0..63: per-graph CSR (LDS histogram -> scan -> LDS-cursor fill).
// Blocks 64..67: bf16 W2 fragment table (4096 items).
// NOTE (r16 lesson): x stays f32 — bf16-izing conv1's inputs perturbs s1 by
// ~1e-3, which flips top-k boundary ranks vs the reference (top-k is
// discontinuous in the score). Only post-selection tensors are bf16.
// ---------------------------------------------------------------------------
__global__ __launch_bounds__(1024) void k_csr(
    const int* __restrict__ src, const int* __restrict__ dst,
    int* __restrict__ rowptr, int* __restrict__ col,
    const float* __restrict__ W2rel, const float* __restrict__ W2rt,
    unsigned short* __restrict__ Wfrag) {
  int g = blockIdx.x, t = threadIdx.x;
  if (g >= BATCH) {                           // Wfrag builder blocks
    int id = (g - BATCH) * 1024 + t;          // 0..4095
    int lane = id & 63, sg = (id >> 6) & 7, c = id >> 9;
    const float* SW = (sg < 4) ? W2rel : W2rt;
    int o = c * 16 + (lane & 15);
    int k = (sg & 3) * 32 + (lane >> 4) * 8;
    float4 f0 = *(const float4*)(SW + (size_t)o * NH + k);
    float4 f1 = *(const float4*)(SW + (size_t)o * NH + k + 4);
    union { unsigned short us[8]; uint4 v; } p;
    p.us[0] = f2bf(f0.x); p.us[1] = f2bf(f0.y);
    p.us[2] = f2bf(f0.z); p.us[3] = f2bf(f0.w);
    p.us[4] = f2bf(f1.x); p.us[5] = f2bf(f1.y);
    p.us[6] = f2bf(f1.z); p.us[7] = f2bf(f1.w);
    *(uint4*)(Wfrag + (size_t)id * 8) = p.v;
    return;
  }
  __shared__ int cnt[NPG];
  int ebase = g * EPG;
  cnt[t] = 0;
  __syncthreads();
  int dl[8], sl[8];
#pragma unroll
  for (int i = 0; i < 8; ++i) {
    int e = ebase + t + i * 1024;
    dl[i] = dst[e] - g * NPG;
    sl[i] = src[e];
    atomicAdd(&cnt[dl[i]], 1);
  }
  __syncthreads();
  int v = cnt[t];
  for (int d = 1; d < NPG; d <<= 1) {       // inclusive scan, in place
    int add = (t >= d) ? cnt[t - d] : 0;
    __syncthreads();
    cnt[t] += add;
    __syncthreads();
  }
  int excl = cnt[t] - v;
  rowptr[g * NPG + t] = ebase + excl;
  if (g == 0 && t == 0) rowptr[NODES] = EDGES;
  __syncthreads();
  cnt[t] = excl;                            // becomes local cursor
  __syncthreads();
#pragma unroll
  for (int i = 0; i < 8; ++i) {
    int pos = atomicAdd(&cnt[dl[i]], 1);
    col[ebase + pos] = sl[i];
  }
}

// ---------------------------------------------------------------------------
// conv1 aggregation via CSR gather over f32 x (score-path precision).
// XCD-swizzled; high occupancy, unfused (r9/r10 lesson).
// ---------------------------------------------------------------------------
__global__ __launch_bounds__(256) void k_gather1(
    const float* __restrict__ x, const int* __restrict__ rowptr,
    const int* __restrict__ col, float* __restrict__ agg1) {
  int bid = blockIdx.x;                       // 4096 blocks, 512 per XCD chunk
  int swz = (bid & 7) * 512 + (bid >> 3);
  int t = threadIdx.x;
  int gi = t >> 4, l = t & 15;
  int n = swz * 16 + gi;
  int rs = rowptr[n], re = rowptr[n + 1];
  if (l < FIN) {
    float acc = 0.f;
    for (int j = rs; j < re; ++j) {
      int v = col[j];
      acc += x[(size_t)v * FIN + l];
    }
    agg1[(size_t)n * FIN + l] = acc;
  }
}

// ---------------------------------------------------------------------------
// conv1 GEMM + relu + fused pool1 score; OUTPUT IS BF16 (h only; s1 is f32
// from f32 inputs -> top-k decisions match reference). LDS stride ASTR=15.
// ---------------------------------------------------------------------------
__global__ __launch_bounds__(256) void k_gemm1(
    const float* __restrict__ x, const float* __restrict__ agg1,
    const float* __restrict__ Wrel, const float* __restrict__ brel,
    const float* __restrict__ Wroot, const float* __restrict__ p1w,
    unsigned short* __restrict__ hbf1, float* __restrict__ s1) {
  __shared__ float As[64 * ASTR];
  __shared__ float Xs[64 * ASTR];
  __shared__ float Wl[2 * FIN][NH];
  int t = threadIdx.x;
  int nb = blockIdx.x * 64;
  for (int i = t; i < 64 * FIN; i += 256) {
    int n = i / FIN, k = i - n * FIN;
    As[n * ASTR + k] = agg1[(size_t)nb * FIN + i];
    Xs[n * ASTR + k] = x[(size_t)nb * FIN + i];
  }
  for (int i = t; i < NH * FIN; i += 256) {
    int o = i / FIN, k = i - o * FIN;
    Wl[k][o]       = Wrel[i];
    Wl[k + FIN][o] = Wroot[i];
  }
  __syncthreads();
  int og = t & 15, ng = t >> 4, ra = ng * 4;
  float bb[8], pw[8];
#pragma unroll
  for (int j = 0; j < 4; ++j) {
    int c0 = og * 4 + j, c1 = 64 + og * 4 + j;
    bb[j] = brel[c0]; bb[j + 4] = brel[c1];
    pw[j] = p1w[c0];  pw[j + 4] = p1w[c1];
  }
  float q = 0.f;
#pragma unroll
  for (int j = 0; j < 8; ++j) q += pw[j] * pw[j];
  q += __shfl_xor(q, 1); q += __shfl_xor(q, 2);
  q += __shfl_xor(q, 4); q += __shfl_xor(q, 8);
  float rnorm = rsqrtf(q);

  float acc[4][8];
#pragma unroll
  for (int i = 0; i < 4; ++i)
#pragma unroll
    for (int j = 0; j < 8; ++j) acc[i][j] = bb[j];
#pragma unroll
  for (int k = 0; k < FIN; ++k) {
    float4 w0 = *(const float4*)&Wl[k][og * 4];
    float4 w1 = *(const float4*)&Wl[k][64 + og * 4];
#pragma unroll
    for (int i = 0; i < 4; ++i) {
      float a = As[(ra + i) * ASTR + k];
      acc[i][0] += a * w0.x; acc[i][1] += a * w0.y;
      acc[i][2] += a * w0.z; acc[i][3] += a * w0.w;
      acc[i][4] += a * w1.x; acc[i][5] += a * w1.y;
      acc[i][6] += a * w1.z; acc[i][7] += a * w1.w;
    }
  }
#pragma unroll
  for (int k = 0; k < FIN; ++k) {
    float4 w0 = *(const float4*)&Wl[FIN + k][og * 4];
    float4 w1 = *(const float4*)&Wl[FIN + k][64 + og * 4];
#pragma unroll
    for (int i = 0; i < 4; ++i) {
      float a = Xs[(ra + i) * ASTR + k];
      acc[i][0] += a * w0.x; acc[i][1] += a * w0.y;
      acc[i][2] += a * w0.z; acc[i][3] += a * w0.w;
      acc[i][4] += a * w1.x; acc[i][5] += a * w1.y;
      acc[i][6] += a * w1.z; acc[i][7] += a * w1.w;
    }
  }
#pragma unroll
  for (int i = 0; i < 4; ++i) {
    int n = nb + ra + i;
    float pv = 0.f;
    union { unsigned short us[4]; uint2 v; } o0, o1;
#pragma unroll
    for (int j = 0; j < 4; ++j) {
      float v0 = fmaxf(acc[i][j], 0.f);
      float v1 = fmaxf(acc[i][4 + j], 0.f);
      pv += v0 * pw[j] + v1 * pw[4 + j];
      o0.us[j] = f2bf(v0);
      o1.us[j] = f2bf(v1);
    }
    *(uint2*)(hbf1 + (size_t)n * NH + og * 4) = o0.v;
    *(uint2*)(hbf1 + (size_t)n * NH + 64 + og * 4) = o1.v;
    pv += __shfl_xor(pv, 1);
    pv += __shfl_xor(pv, 2);
    pv += __shfl_xor(pv, 4);
    pv += __shfl_xor(pv, 8);
    if (og == 0) s1[n] = tanhf(pv * rnorm);
  }
}

// ---------------------------------------------------------------------------
// exact per-graph top-K: 512 threads, bitonic over 1024 keys; j<=64 stages
// are wave-local. Writes sm_out[n]=kept?score:0 and (optional) kept[].
// ---------------------------------------------------------------------------
__global__ __launch_bounds__(512) void k_topk(
    const float* __restrict__ score, const float* __restrict__ mask_sm,
    int* __restrict__ kept, float* __restrict__ sm_out, int K) {
  __shared__ unsigned long long keys[1024];
  int t = threadIdx.x, g = blockIdx.x;
  for (int i = t; i < 1024; i += 512) {
    int n = g * NPG + i;
    unsigned int inv;
    if (mask_sm && mask_sm[n] == 0.f) {
      inv = 0xFFFFFFFFu;
    } else {
      unsigned int u   = __float_as_uint(score[n]);
      unsigned int ord = (u & 0x80000000u) ? ~u : (u | 0x80000000u);
      inv = ~ord;
    }
    keys[i] = ((unsigned long long)inv << 32) | (unsigned int)i;
  }
  __syncthreads();
  for (int k = 2; k <= 1024; k <<= 1) {
    int j = k >> 1;
    for (; j >= 128; j >>= 1) {            // cross-wave stages
      int i = ((t & ~(j - 1)) << 1) | (t & (j - 1));
      int p = i | j;
      unsigned long long a = keys[i], b = keys[p];
      bool up = ((i & k) == 0);
      if ((a > b) == up) { keys[i] = b; keys[p] = a; }
      __syncthreads();
    }
    for (; j > 0; j >>= 1) {               // wave-local stages
      int i = ((t & ~(j - 1)) << 1) | (t & (j - 1));
      int p = i | j;
      unsigned long long a = keys[i], b = keys[p];
      bool up = ((i & k) == 0);
      if ((a > b) == up) { keys[i] = b; keys[p] = a; }
      asm volatile("" ::: "memory");
    }
    __syncthreads();
  }
  for (int i = t; i < 1024; i += 512) {
    int idx = (int)(keys[i] & 0xFFFFFFFFu);
    int n = g * NPG + idx;
    int kp = (i < K) ? 1 : 0;
    if (kept) kept[n] = kp;
    sm_out[n] = kp ? score[n] : 0.f;
  }
}

// ---------------------------------------------------------------------------
// MERGED dispatch: gather2 (blocks 0..16383) + readout1 (blocks 16384..17407).
// readout1 gates on s1m != 0 (single array; kept nodes have s!=0 a.s.).
// NO device-scope fences (r14 lesson: __threadfence in BW-bound kernel =
// L2 writeback storm, 10x slowdown).
// ---------------------------------------------------------------------------
__global__ __launch_bounds__(256) void k_gather2ro(
    const unsigned short* __restrict__ hbf1, const float* __restrict__ s1m,
    const int* __restrict__ rowptr, const int* __restrict__ col,
    const int* __restrict__ kept1, unsigned short* __restrict__ agg2bf,
    float* __restrict__ psum, float* __restrict__ pmax) {
  int bid = blockIdx.x;
  if (bid >= NG2BLK) {                        // ---- readout1 path ----
    int rb = bid - NG2BLK;                    // 0..1023
    int g = rb >> 4, c = rb & 15;
    int f = threadIdx.x & 127, half = threadIdx.x >> 7;
    int nbase = g * NPG + c * 64 + half;
    float sum = 0.f, mx = -1e30f;
    for (int i = 0; i < 64; i += 2) {
      int n = nbase + i;
      float sk = s1m[n];
      if (sk != 0.f) {
        float v = bf2f(hbf1[(size_t)n * NH + f]) * sk;
        sum += v;
        mx = fmaxf(mx, v);
      }
    }
    int slot = rb * 2 + half;
    psum[(size_t)slot * NH + f] = sum;
    pmax[(size_t)slot * NH + f] = mx;
    return;
  }
  // ---- gather2 path ----
  int swz = (bid & 7) * 2048 + (bid >> 3);
  int wave = threadIdx.x >> 6, lane = threadIdx.x & 63;
  int d = swz * 4 + wave;
  if (!kept1[d]) return;                      // row never consumed downstream
  int rs = rowptr[d], re = rowptr[d + 1];
  int deg = re - rs;
  int colv = 0; float sv = 0.f;
  if (lane < deg) {
    colv = col[rs + lane];
    sv = s1m[colv];
  }
  int m = deg < 64 ? deg : 64;
  float ax = 0.f, ay = 0.f;
  int nfull = m & ~3;
  int j = 0;
  for (; j < nfull; j += 4) {
    int v0 = __shfl(colv, j);
    int v1 = __shfl(colv, j + 1);
    int v2 = __shfl(colv, j + 2);
    int v3 = __shfl(colv, j + 3);
    float f0 = __shfl(sv, j);
    float f1 = __shfl(sv, j + 1);
    float f2 = __shfl(sv, j + 2);
    float f3 = __shfl(sv, j + 3);
    unsigned int p0 = *(const unsigned int*)(hbf1 + (size_t)v0 * NH + lane * 2);
    unsigned int p1 = *(const unsigned int*)(hbf1 + (size_t)v1 * NH + lane * 2);
    unsigned int p2 = *(const unsigned int*)(hbf1 + (size_t)v2 * NH + lane * 2);
    unsigned int p3 = *(const unsigned int*)(hbf1 + (size_t)v3 * NH + lane * 2);
    ax += bf2f(p0 & 0xffff) * f0 + bf2f(p1 & 0xffff) * f1 +
          bf2f(p2 & 0xffff) * f2 + bf2f(p3 & 0xffff) * f3;
    ay += bf2f(p0 >> 16) * f0 + bf2f(p1 >> 16) * f1 +
          bf2f(p2 >> 16) * f2 + bf2f(p3 >> 16) * f3;
  }
  for (; j < m; ++j) {
    int v = __shfl(colv, j);
    float f = __shfl(sv, j);
    unsigned int p = *(const unsigned int*)(hbf1 + (size_t)v * NH + lane * 2);
    ax += bf2f(p & 0xffff) * f;
    ay += bf2f(p >> 16) * f;
  }
  for (int jj = rs + 64; jj < re; ++jj) {      // deg>64 fallback (≈never)
    int v = col[jj];
    float f = s1m[v];
    unsigned int p = *(const unsigned int*)(hbf1 + (size_t)v * NH + lane * 2);
    ax += bf2f(p & 0xffff) * f;
    ay += bf2f(p >> 16) * f;
  }
  unsigned int packed = ((unsigned int)f2bf(ay) << 16) | (unsigned int)f2bf(ax);
  *(unsigned int*)(agg2bf + (size_t)d * NH + lane * 2) = packed;
}

// ---------------------------------------------------------------------------
// conv2 GEMM via bf16 MFMA — barrier-free, LDS-free. 2 row-groups/wave
// (W fragment reuse x2). A: agg2bf direct; root = hbf1*s1m (in-register).
// Output h2 is bf16, gated. Dropped rows: finite poison in, masked out.
// D layout: col=lane&15, row=(lane>>4)*4+reg (m89). XCD-swizzled.
// ---------------------------------------------------------------------------
__global__ __launch_bounds__(256) void k_gemm2(
    const unsigned short* __restrict__ agg2bf,
    const unsigned short* __restrict__ hbf1, const float* __restrict__ s1m,
    const int* __restrict__ kept1, const unsigned short* __restrict__ Wfrag,
    const float* __restrict__ b2, const float* __restrict__ p2w,
    unsigned short* __restrict__ h2bf, float* __restrict__ s2) {
  int t = threadIdx.x;
  int bid = blockIdx.x;                 // 512 blocks, 64 per XCD chunk
  int swz = (bid & 7) * 64 + (bid >> 3);
  int nb = swz * 128;
  int lane = t & 63, w = t >> 6;
  int row16 = lane & 15, kgrp = lane >> 4;
  int base = nb + 32 * w;               // wave owns rows base..base+31
  int r0 = base + row16, r1 = base + 16 + row16;

  // ---- A fragments ----
  bf16x8 a0[8], a1[8];
#pragma unroll
  for (int s = 0; s < 4; ++s) {
    int k = s * 32 + kgrp * 8;
    a0[s] = *(const bf16x8*)(agg2bf + (size_t)r0 * NH + k);
    a1[s] = *(const bf16x8*)(agg2bf + (size_t)r1 * NH + k);
  }
  {
    float sc0 = s1m[r0], sc1 = s1m[r1];
    const unsigned short* S0 = hbf1 + (size_t)r0 * NH;
    const unsigned short* S1 = hbf1 + (size_t)r1 * NH;
#pragma unroll
    for (int s = 0; s < 4; ++s) {
      int k = s * 32 + kgrp * 8;
      union { unsigned short us[8]; uint4 v; } i0, i1;
      i0.v = *(const uint4*)(S0 + k);
      i1.v = *(const uint4*)(S1 + k);
      union { unsigned short us[8]; bf16x8 v; } p, q;
#pragma unroll
      for (int u = 0; u < 8; ++u) {
        p.us[u] = f2bf(bf2f(i0.us[u]) * sc0);
        q.us[u] = f2bf(bf2f(i1.us[u]) * sc1);
      }
      a0[4 + s] = p.v;
      a1[4 + s] = q.v;
    }
  }

  // ---- MFMA: stream W fragments from L2, reuse x2 ----
  f32x4 acc0[8], acc1[8];
#pragma unroll
  for (int c = 0; c < 8; ++c) {
    acc0[c] = (f32x4){0.f, 0.f, 0.f, 0.f};
    acc1[c] = (f32x4){0.f, 0.f, 0.f, 0.f};
  }
  const bf16x8* WF = (const bf16x8*)Wfrag;
#pragma unroll
  for (int c = 0; c < 8; ++c) {
#pragma unroll
    for (int s = 0; s < 8; ++s) {
      bf16x8 wv = WF[(c * 8 + s) * 64 + lane];
      acc0[c] = __builtin_amdgcn_mfma_f32_16x16x32_bf16(a0[s], wv, acc0[c], 0, 0, 0);
      acc1[c] = __builtin_amdgcn_mfma_f32_16x16x32_bf16(a1[s], wv, acc1[c], 0, 0, 0);
    }
  }

  // ---- epilogue ----
  float bb[8], pw[8];
#pragma unroll
  for (int c = 0; c < 8; ++c) {
    bb[c] = b2[c * 16 + row16];
    pw[c] = p2w[c * 16 + row16];
  }
  float q2 = 0.f;
#pragma unroll
  for (int c = 0; c < 8; ++c) q2 += pw[c] * pw[c];
  q2 += __shfl_xor(q2, 1); q2 += __shfl_xor(q2, 2);
  q2 += __shfl_xor(q2, 4); q2 += __shfl_xor(q2, 8);
  float rnorm = rsqrtf(q2);

#pragma unroll
  for (int g2 = 0; g2 < 2; ++g2) {
    f32x4* acc = g2 ? acc1 : acc0;
    int rbase = base + g2 * 16;
    int msr[4];
#pragma unroll
    for (int r = 0; r < 4; ++r) msr[r] = kept1[rbase + kgrp * 4 + r];
    float pvp[4] = {0.f, 0.f, 0.f, 0.f};
#pragma unroll
    for (int c = 0; c < 8; ++c) {
#pragma unroll
      for (int r = 0; r < 4; ++r) {
        float u = fmaxf(acc[c][r] + bb[c], 0.f);
        pvp[r] += u * pw[c];
        if (msr[r]) {                    // kept2 subset of kept1 -> safe skip
          int n = rbase + kgrp * 4 + r;
          h2bf[(size_t)n * NH + c * 16 + row16] = f2bf(u);
        }
      }
    }
#pragma unroll
    for (int r = 0; r < 4; ++r) {
      float pv = pvp[r];
      pv += __shfl_xor(pv, 1);
      pv += __shfl_xor(pv, 2);
      pv += __shfl_xor(pv, 4);
      pv += __shfl_xor(pv, 8);
      if (row16 == 0) {
        int n = rbase + kgrp * 4 + r;
        s2[n] = tanhf(pv * rnorm);
      }
    }
  }
}

// ---------------------------------------------------------------------------
// readout2 partials — gates on s2m != 0 (no kept2 buffer)
// ---------------------------------------------------------------------------
__global__ __launch_bounds__(256) void k_readout2(
    const unsigned short* __restrict__ h, const float* __restrict__ s2m,
    float* __restrict__ psum, float* __restrict__ pmax) {
  int g = blockIdx.x >> 4, c = blockIdx.x & 15;
  int f = threadIdx.x & 127, half = threadIdx.x >> 7;
  int nbase = g * NPG + c * 64 + half;
  float sum = 0.f, mx = -1e30f;
  for (int i = 0; i < 64; i += 2) {
    int n = nbase + i;
    float sk = s2m[n];
    if (sk != 0.f) {
      float v = bf2f(h[(size_t)n * NH + f]) * sk;
      sum += v;
      mx = fmaxf(mx, v);
    }
  }
  int slot = blockIdx.x * 2 + half;
  psum[(size_t)slot * NH + f] = sum;
  pmax[(size_t)slot * NH + f] = mx;
}

// ---------------------------------------------------------------------------
// final combine (32 partial slots per graph per layer)
// ---------------------------------------------------------------------------
__global__ __launch_bounds__(256) void k_final(
    const float* __restrict__ psum1, const float* __restrict__ pmax1,
    const float* __restrict__ psum2, const float* __restrict__ pmax2,
    float* __restrict__ out) {
  int g = blockIdx.x, t = threadIdx.x;
  if (t < 128) {
    float a = 0.f, b = 0.f;
#pragma unroll
    for (int c = 0; c < 32; ++c) {
      a += psum1[(size_t)(g * 32 + c) * NH + t];
      b += psum2[(size_t)(g * 32 + c) * NH + t];
    }
    out[(size_t)g * 256 + t] = a / (float)KP1 + b / (float)KP2;
  } else {
    int f = t - 128;
    float a = -1e30f, b = -1e30f;
#pragma unroll
    for (int c = 0; c < 32; ++c) {
      a = fmaxf(a, pmax1[(size_t)(g * 32 + c) * NH + f]);
      b = fmaxf(b, pmax2[(size_t)(g * 32 + c) * NH + f]);
    }
    out[(size_t)g * 256 + t] = a + b;
  }
}

// ---------------------------------------------------------------------------
extern "C" void kernel_launch(void* const* d_in, const int* in_sizes, int n_in,
                              void* d_out, int out_size, void* d_ws, size_t ws_size,
                              hipStream_t stream) {
  const float* x     = (const float*)d_in[0];
  const int*   eidx  = (const int*)d_in[1];
  const int*   src   = eidx;
  const int*   dst   = eidx + EDGES;
  const float* W1rel = (const float*)d_in[3];
  const float* b1    = (const float*)d_in[4];
  const float* W1rt  = (const float*)d_in[5];
  const float* p1w   = (const float*)d_in[6];
  const float* W2rel = (const float*)d_in[7];
  const float* b2    = (const float*)d_in[8];
  const float* W2rt  = (const float*)d_in[9];
  const float* p2w   = (const float*)d_in[10];
  float* out = (float*)d_out;

  // workspace layout (floats)
  float* ws = (float*)d_ws;
  size_t off = 0;
  unsigned short* hbf1   = (unsigned short*)(ws + off); off += (size_t)NODES * NH / 2;
  unsigned short* h2bf   = (unsigned short*)(ws + off); off += (size_t)NODES * NH / 2;
  unsigned short* agg2bf = (unsigned short*)(ws + off); off += (size_t)NODES * NH / 2;
  float* agg1  = ws + off; off += (size_t)NODES * FIN;
  float* s1    = ws + off; off += NODES;
  float* s2    = ws + off; off += NODES;
  float* s1m   = ws + off; off += NODES;
  float* s2m   = ws + off; off += NODES;
  int*   kept1 = (int*)(ws + off); off += NODES;
  float* psum1 = ws + off; off += 2048 * NH;
  float* pmax1 = ws + off; off += 2048 * NH;
  float* psum2 = ws + off; off += 2048 * NH;
  float* pmax2 = ws + off; off += 2048 * NH;
  unsigned short* Wfrag = (unsigned short*)(ws + off); off += 16384; // 64 KB
  int*   rowptr  = (int*)(ws + off); off += NODES + 1;
  int*   col     = (int*)(ws + off); off += EDGES;

  // ---- CSR build + W fragment prep (one dispatch) ----
  k_csr<<<BATCH + 4, 1024, 0, stream>>>(src, dst, rowptr, col, W2rel, W2rt,
                                        Wfrag);

  // ---- layer 1 ----
  k_gather1<<<NODES / 16, 256, 0, stream>>>(x, rowptr, col, agg1);
  k_gemm1<<<NODES / 64, 256, 0, stream>>>(x, agg1, W1rel, b1, W1rt, p1w,
                                          hbf1, s1);
  k_topk<<<BATCH, 512, 0, stream>>>(s1, nullptr, kept1, s1m, KP1);

  // ---- merged: conv2 gather + layer-1 readout ----
  k_gather2ro<<<NG2BLK + 1024, 256, 0, stream>>>(hbf1, s1m, rowptr, col,
                                                 kept1, agg2bf, psum1, pmax1);

  // ---- layer 2 ----
  k_gemm2<<<NODES / 128, 256, 0, stream>>>(agg2bf, hbf1, s1m, kept1, Wfrag,
                                           b2, p2w, h2bf, s2);
  k_topk<<<BATCH, 512, 0, stream>>>(s2, s1m, nullptr, s2m, KP2);
  k_readout2<<<1024, 256, 0, stream>>>(h2bf, s2m, psum2, pmax2);
  k_final<<<BATCH, 256, 0, stream>>>(psum1, pmax1, psum2, pmax2, out);
}